// Round 6
// baseline (1213.872 us; speedup 1.0000x reference)
//
#include <hip/hip_runtime.h>

// Sggnn_23218593202512 — round 6: barrier-free K-loop. R5 showed all pipes
// idle at 42% occupancy -> limiter is the per-iter vmcnt(0)+barrier drain
// (32 serial DMA round-trips per block at K=1024). New gemm_blds: B-panel
// (64 cols x 512 K-half, 64 KiB) LDS-resident per block; A streamed straight
// into MFMA a-frags via global bf16x8 loads; K-loop has ZERO barriers
// (4 barriers/block total, at B-panel (re)loads). Pair-construction moved to
// a materialization kernel (d/dg bf16 chunks). XCD-grouped decode: each XCD
// owns 1/8 of A rows (L2 reuse across its 16 col-blocks).
//
// Pipeline: prep BN folds -> wtrans -> 4x[pair(dg qtr) + affinity gemm_blds
// fused->w_acc] -> wconv -> per probe-chunk: pair(d) -> h -> t -> u ->
// utrans -> featfused (R5 gemm_kernel, verified) -> finout.

typedef __bf16 bf16;
typedef __attribute__((ext_vector_type(8))) __bf16 bf16x8;
typedef __attribute__((ext_vector_type(4))) float f32x4;

#define EPSV 1e-5f

__device__ __forceinline__ void async_load16(const bf16* g, bf16* l) {
    __builtin_amdgcn_global_load_lds(
        (const __attribute__((address_space(1))) void*)g,
        (__attribute__((address_space(3))) void*)l, 16, 0, 0);
}

__global__ __launch_bounds__(256) void prep_kernel(
    const float* __restrict__ g, const float* __restrict__ b,
    const float* __restrict__ m, const float* __restrict__ v,
    const float* __restrict__ bias, float* __restrict__ scale,
    float* __restrict__ offset, int n)
{
    int i = blockIdx.x * 256 + threadIdx.x;
    if (i >= n) return;
    float s = g[i] / sqrtf(v[i] + EPSV);
    float o = b[i] - m[i] * s;
    if (bias) o += bias[i] * s;
    scale[i] = s;
    offset[i] = o;
}

__global__ __launch_bounds__(256) void wtrans_kernel(
    const float* __restrict__ in, bf16* __restrict__ out, int K, int N)
{
    int k = blockIdx.x * 256 + threadIdx.x;
    int n = blockIdx.y;
    out[(size_t)n * K + k] = (bf16)in[(size_t)k * N + n];
}

// D[r][kc..kc+7] = bf16((X[(roff+r)>>8][k]-Y[(roff+r)&255][k])^2*ps[k]+po[k])
__global__ __launch_bounds__(256) void pair_kernel(
    const float* __restrict__ X, const float* __restrict__ Y,
    const float* __restrict__ ps, const float* __restrict__ po,
    bf16* __restrict__ D, int roff)
{
    int gid = blockIdx.x * 256 + threadIdx.x;
    int r = gid >> 7, kc = (gid & 127) * 8;
    int rg = roff + r;
    const float* xp = X + (size_t)(rg >> 8) * 1024 + kc;
    const float* yp = Y + (size_t)(rg & 255) * 1024 + kc;
    f32x4 x0 = *(const f32x4*)xp, x1 = *(const f32x4*)(xp + 4);
    f32x4 y0 = *(const f32x4*)yp, y1 = *(const f32x4*)(yp + 4);
    f32x4 sa = *(const f32x4*)(ps + kc), sb = *(const f32x4*)(ps + kc + 4);
    f32x4 oa = *(const f32x4*)(po + kc), ob = *(const f32x4*)(po + kc + 4);
    bf16x8 dv;
#pragma unroll
    for (int j = 0; j < 4; ++j) {
        float d0 = x0[j] - y0[j], d1 = x1[j] - y1[j];
        dv[j]     = (bf16)(d0 * d0 * sa[j] + oa[j]);
        dv[j + 4] = (bf16)(d1 * d1 * sb[j] + ob[j]);
    }
    *(bf16x8*)(D + (size_t)r * 1024 + kc) = dv;
}

// wT[g2*256+g1] = bf16(w_acc[g1*256+g2] + scl_b)
__global__ __launch_bounds__(256) void wconv_kernel(
    const float* __restrict__ w_acc, const float* __restrict__ sclb,
    bf16* __restrict__ wT)
{
    int tid = blockIdx.x * 256 + threadIdx.x;
    int g2 = tid >> 8, g1 = tid & 255;
    wT[tid] = (bf16)(w_acc[g1 * 256 + g2] + sclb[0]);
}

__global__ __launch_bounds__(256) void utrans_kernel(
    const bf16* __restrict__ u, bf16* __restrict__ uT)
{
    __shared__ float tile[64][65];
    int g0 = blockIdx.x * 64, h0 = blockIdx.y * 64, p = blockIdx.z;
    const bf16* up = u + (size_t)p * 256 * 512;
    bf16* op = uT + (size_t)p * 512 * 256;
    for (int c = threadIdx.x; c < 512; c += 256) {
        int r = c >> 3, hc = (c & 7) * 8;
        bf16x8 val = *(const bf16x8*)(up + (size_t)(g0 + r) * 512 + h0 + hc);
#pragma unroll
        for (int j = 0; j < 8; ++j) tile[r][hc + j] = (float)val[j];
    }
    __syncthreads();
    for (int c = threadIdx.x; c < 512; c += 256) {
        int hr = c >> 3, gc = (c & 7) * 8;
        bf16x8 val;
#pragma unroll
        for (int j = 0; j < 8; ++j) val[j] = (bf16)tile[gc + j][hr];
        *(bf16x8*)(op + (size_t)(h0 + hr) * 256 + g0 + gc) = val;
    }
}

__global__ __launch_bounds__(256) void finout_kernel(
    const float* __restrict__ acc, const float* __restrict__ clsb,
    float* __restrict__ out)
{
    int i = blockIdx.x * 256 + threadIdx.x;
    out[i] = acc[i] + clsb[0];
}

// ---------- barrier-free-K GEMM: C[M,N] = epi(A[M,1024] @ BT[N,1024]^T) ----
// 512 thr = 8 waves (4 row x 2 col), wave tile 64x32 (acc[4][2]).
// B half-panel 64 cols x 512 K in LDS (64 KiB, XOR-swizzled 16B chunks);
// A streamed as direct global bf16x8 frag loads. No barriers in K-loop.
// Block decode: b&7 = XCD slot, each owns nRowB/8 row-groups x nColB cols.
// fuseW: rs += lrelu(bn(val))*fuseW[col] -> atomicAdd facc[row]
__global__ __launch_bounds__(512) void gemm_blds(
    const bf16* __restrict__ A, const bf16* __restrict__ BT,
    bf16* __restrict__ C, int N, int nColB, int nRowBdiv8,
    const float* __restrict__ scale, const float* __restrict__ offset,
    int lrelu, const float* __restrict__ fuseW, float* __restrict__ facc)
{
    __shared__ bf16 Bs[64 * 512];   // 64 KiB
    const int tid  = threadIdx.x;
    const int lane = tid & 63;
    const int wave = tid >> 6;
    const int wrow = wave >> 1, wcol = wave & 1;
    const int q = lane >> 4, l16 = lane & 15;

    int b = blockIdx.x;
    int xcd = b & 7, j = b >> 3;
    int colb = j % nColB, rl = j / nColB;
    int rowb = xcd * nRowBdiv8 + rl;
    const int row0 = rowb * 256, col0 = colb * 64;

    f32x4 acc[4][2];
#pragma unroll
    for (int mi = 0; mi < 4; ++mi)
#pragma unroll
        for (int ni = 0; ni < 2; ++ni)
#pragma unroll
            for (int e = 0; e < 4; ++e) acc[mi][ni][e] = 0.f;

    const bf16* Arow[4];
#pragma unroll
    for (int mi = 0; mi < 4; ++mi)
        Arow[mi] = A + (size_t)(row0 + wrow * 64 + mi * 16 + l16) * 1024;

    for (int kh = 0; kh < 2; ++kh) {
        // stage B half-panel: 64 cols x 512 K, swizzled chunk = ch ^ (c&7)
#pragma unroll
        for (int i = 0; i < 8; ++i) {
            int idx = i * 512 + tid;            // 4096 16B-chunks
            int c = idx >> 6, chs = idx & 63;
            int ch = chs ^ (c & 7);
            async_load16(BT + (size_t)(col0 + c) * 1024 + kh * 512 + ch * 8,
                         &Bs[idx * 8]);
        }
        __syncthreads();

#pragma unroll 2
        for (int it = 0; it < 16; ++it) {
            bf16x8 af[4], bfr[2];
            int ko = kh * 512 + it * 32 + q * 8;
#pragma unroll
            for (int mi = 0; mi < 4; ++mi)
                af[mi] = *(const bf16x8*)(Arow[mi] + ko);
#pragma unroll
            for (int ni = 0; ni < 2; ++ni) {
                int c = wcol * 32 + ni * 16 + l16;
                int chs = (it * 4 + q) ^ (c & 7);
                bfr[ni] = *(const bf16x8*)&Bs[(c * 64 + chs) * 8];
            }
#pragma unroll
            for (int mi = 0; mi < 4; ++mi)
#pragma unroll
                for (int ni = 0; ni < 2; ++ni)
                    acc[mi][ni] = __builtin_amdgcn_mfma_f32_16x16x32_bf16(
                        af[mi], bfr[ni], acc[mi][ni], 0, 0, 0);
        }
        __syncthreads();
    }

    // C/D layout: col = lane&15, row = (lane>>4)*4 + reg
    if (fuseW) {
#pragma unroll
        for (int mi = 0; mi < 4; ++mi)
#pragma unroll
            for (int i = 0; i < 4; ++i) {
                float rs = 0.f;
#pragma unroll
                for (int ni = 0; ni < 2; ++ni) {
                    int cc = col0 + wcol * 32 + ni * 16 + l16;
                    float val = acc[mi][ni][i] * scale[cc] + offset[cc];
                    val = val > 0.f ? val : 0.1f * val;
                    rs += val * fuseW[cc];
                }
                rs += __shfl_xor(rs, 1, 64);
                rs += __shfl_xor(rs, 2, 64);
                rs += __shfl_xor(rs, 4, 64);
                rs += __shfl_xor(rs, 8, 64);
                if (l16 == 0) {
                    int r = row0 + wrow * 64 + mi * 16 + q * 4 + i;
                    atomicAdd(facc + r, rs);
                }
            }
        return;
    }
#pragma unroll
    for (int mi = 0; mi < 4; ++mi)
#pragma unroll
        for (int ni = 0; ni < 2; ++ni)
#pragma unroll
            for (int i = 0; i < 4; ++i) {
                int r = row0 + wrow * 64 + mi * 16 + q * 4 + i;
                int cc = col0 + wcol * 32 + ni * 16 + l16;
                float val = acc[mi][ni][i];
                if (scale) val = val * scale[cc] + offset[cc];
                if (lrelu) val = val > 0.f ? val : 0.1f * val;
                C[(size_t)r * N + cc] = (bf16)val;
            }
}

// ---------- R5 gemm (verified) kept for the batched featfused stage --------
__global__ __launch_bounds__(256) void gemm_kernel(
    const bf16* __restrict__ A,
    const bf16* __restrict__ BT, bf16* __restrict__ C,
    int K, int N, long long batchB, long long batchC,
    const float* __restrict__ scale, const float* __restrict__ offset,
    int lrelu, const float* __restrict__ fuseW, float* __restrict__ facc,
    long long faccStride)
{
    __shared__ bf16 As[128 * 64];
    __shared__ bf16 Bs[64 * 64];
    const int tid  = threadIdx.x;
    const int lane = tid & 63;
    const int wave = tid >> 6;
    const int wr = wave >> 1, wc = wave & 1;
    const int row0 = blockIdx.y * 128;
    const int col0 = blockIdx.x * 64;
    const int q = lane >> 4, l16 = lane & 15;
    const int arow = lane >> 3;
    const int gch  = (lane & 7) ^ (arow & 7);

    const bf16* Bp = BT + (size_t)blockIdx.z * (size_t)batchB;
    bf16* Cp = C + (size_t)blockIdx.z * (size_t)batchC;

    f32x4 acc[4][2];
#pragma unroll
    for (int mi = 0; mi < 4; ++mi)
#pragma unroll
        for (int ni = 0; ni < 2; ++ni)
#pragma unroll
            for (int e = 0; e < 4; ++e) acc[mi][ni][e] = 0.f;

    for (int kk = 0; kk < K; kk += 64) {
#pragma unroll
        for (int t = 0; t < 4; ++t) {
            int j = wave * 4 + t;
            async_load16(A + (size_t)(row0 + j * 8 + arow) * K + kk + gch * 8,
                         &As[j * 512 + lane * 8]);
        }
#pragma unroll
        for (int t = 0; t < 2; ++t) {
            int j = wave * 2 + t;
            async_load16(Bp + (size_t)(col0 + j * 8 + arow) * K + kk + gch * 8,
                         &Bs[j * 512 + lane * 8]);
        }
        __syncthreads();
#pragma unroll
        for (int s = 0; s < 2; ++s) {
            bf16x8 af[4], bfr[2];
#pragma unroll
            for (int mi = 0; mi < 4; ++mi) {
                int r = wr * 64 + mi * 16 + l16;
                af[mi] = *(const bf16x8*)&As[r * 64 + (((s * 4 + q) ^ (r & 7)) * 8)];
            }
#pragma unroll
            for (int ni = 0; ni < 2; ++ni) {
                int rc = wc * 32 + ni * 16 + l16;
                bfr[ni] = *(const bf16x8*)&Bs[rc * 64 + (((s * 4 + q) ^ (rc & 7)) * 8)];
            }
#pragma unroll
            for (int mi = 0; mi < 4; ++mi)
#pragma unroll
                for (int ni = 0; ni < 2; ++ni)
                    acc[mi][ni] = __builtin_amdgcn_mfma_f32_16x16x32_bf16(
                        af[mi], bfr[ni], acc[mi][ni], 0, 0, 0);
        }
        __syncthreads();
    }

    if (fuseW) {
#pragma unroll
        for (int mi = 0; mi < 4; ++mi)
#pragma unroll
            for (int i = 0; i < 4; ++i) {
                float rs = 0.f;
#pragma unroll
                for (int ni = 0; ni < 2; ++ni) {
                    int cc = col0 + wc * 32 + ni * 16 + l16;
                    float val = acc[mi][ni][i] * scale[cc] + offset[cc];
                    val = val > 0.f ? val : 0.1f * val;
                    rs += val * fuseW[cc];
                }
                rs += __shfl_xor(rs, 1, 64);
                rs += __shfl_xor(rs, 2, 64);
                rs += __shfl_xor(rs, 4, 64);
                rs += __shfl_xor(rs, 8, 64);
                if (l16 == 0) {
                    int r = row0 + wr * 64 + mi * 16 + q * 4 + i;
                    atomicAdd(facc + (size_t)blockIdx.z * faccStride + r, rs);
                }
            }
        return;
    }
#pragma unroll
    for (int mi = 0; mi < 4; ++mi)
#pragma unroll
        for (int ni = 0; ni < 2; ++ni)
#pragma unroll
            for (int i = 0; i < 4; ++i) {
                int r = row0 + wr * 64 + mi * 16 + q * 4 + i;
                int cc = col0 + wc * 32 + ni * 16 + l16;
                float val = acc[mi][ni][i];
                if (scale) val = val * scale[cc] + offset[cc];
                if (lrelu) val = val > 0.f ? val : 0.1f * val;
                Cp[(size_t)r * N + cc] = (bf16)val;
            }
}

extern "C" void kernel_launch(void* const* d_in, const int* in_sizes, int n_in,
                              void* d_out, int out_size, void* d_ws, size_t ws_size,
                              hipStream_t stream)
{
    const float* f_p   = (const float*)d_in[0];
    const float* f_g   = (const float*)d_in[1];
    const float* bn_g  = (const float*)d_in[2];
    const float* bn_b  = (const float*)d_in[3];
    const float* bn_m  = (const float*)d_in[4];
    const float* bn_v  = (const float*)d_in[5];
    const float* rf_W1 = (const float*)d_in[6];
    const float* rf_b1 = (const float*)d_in[7];
    const float* rf1_g = (const float*)d_in[8];
    const float* rf1_b = (const float*)d_in[9];
    const float* rf1_m = (const float*)d_in[10];
    const float* rf1_v = (const float*)d_in[11];
    const float* rf_W2 = (const float*)d_in[12];
    const float* rf_b2 = (const float*)d_in[13];
    const float* rf2_g = (const float*)d_in[14];
    const float* rf2_b = (const float*)d_in[15];
    const float* rf2_m = (const float*)d_in[16];
    const float* rf2_v = (const float*)d_in[17];
    const float* sfc_W = (const float*)d_in[18];
    const float* sfc_b = (const float*)d_in[19];
    const float* sbn_g = (const float*)d_in[20];
    const float* sbn_b = (const float*)d_in[21];
    const float* sbn_m = (const float*)d_in[22];
    const float* sbn_v = (const float*)d_in[23];
    const float* scl_W = (const float*)d_in[24];
    const float* scl_b = (const float*)d_in[25];
    const float* ffc_W = (const float*)d_in[26];
    const float* ffc_b = (const float*)d_in[27];
    const float* fbn_g = (const float*)d_in[28];
    const float* fbn_b = (const float*)d_in[29];
    const float* fbn_m = (const float*)d_in[30];
    const float* fbn_v = (const float*)d_in[31];
    const float* cls_W = (const float*)d_in[32];
    const float* cls_b = (const float*)d_in[33];

    const size_t MB = 1ull << 20;
    char* ws = (char*)d_ws;
    float* SC      = (float*)(ws);
    float *s0 = SC,        *o0 = SC + 1024;
    float *s1 = SC + 2048, *o1 = SC + 3072;
    float *s2 = SC + 4096, *o2 = SC + 5120;
    float *s3 = SC + 6144, *o3 = SC + 6656;
    float *s4 = SC + 7168, *o4 = SC + 7680;
    float* w_acc   = (float*)(ws + 65536);       // 256 KiB
    float* out_acc = (float*)(ws + 327680);      // 128 KiB
    bf16* wT       = (bf16*)(ws + 458752);       // 128 KiB
    bf16* W1T      = (bf16*)(ws + 1 * MB);
    bf16* W2T      = (bf16*)(ws + 3 * MB);
    bf16* sfcT     = (bf16*)(ws + 5 * MB);
    bf16* ffcT     = (bf16*)(ws + 6 * MB);

    int nc = (ws_size >= 125 * MB) ? 2 : 4;      // R3 confirmed ws>=170MB
    const int pc = 128 / nc;
    const int R  = pc * 256;                     // rows per probe chunk
    const size_t dsz = (size_t)R * 1024 * 2;
    bf16* dbuf = (bf16*)(ws + 8 * MB);           // d / dg-quarter / uT
    bf16* hbuf = (bf16*)(ws + 8 * MB + dsz);
    bf16* tbuf = (bf16*)(ws + 8 * MB + 2 * dsz);
    bf16* ubuf = (bf16*)(ws + 8 * MB + 3 * dsz);

    // 1. BN folds
    prep_kernel<<<dim3(4), 256, 0, stream>>>(bn_g, bn_b, bn_m, bn_v, nullptr, s0, o0, 1024);
    prep_kernel<<<dim3(4), 256, 0, stream>>>(rf1_g, rf1_b, rf1_m, rf1_v, rf_b1, s1, o1, 1024);
    prep_kernel<<<dim3(4), 256, 0, stream>>>(rf2_g, rf2_b, rf2_m, rf2_v, rf_b2, s2, o2, 1024);
    prep_kernel<<<dim3(2), 256, 0, stream>>>(sbn_g, sbn_b, sbn_m, sbn_v, sfc_b, s3, o3, 512);
    prep_kernel<<<dim3(2), 256, 0, stream>>>(fbn_g, fbn_b, fbn_m, fbn_v, ffc_b, s4, o4, 512);

    // 2. weight transposes
    wtrans_kernel<<<dim3(4, 1024), 256, 0, stream>>>(rf_W1, W1T, 1024, 1024);
    wtrans_kernel<<<dim3(4, 1024), 256, 0, stream>>>(rf_W2, W2T, 1024, 1024);
    wtrans_kernel<<<dim3(4, 512), 256, 0, stream>>>(sfc_W, sfcT, 1024, 512);
    wtrans_kernel<<<dim3(4, 512), 256, 0, stream>>>(ffc_W, ffcT, 1024, 512);

    // 3. zero accumulators
    hipMemsetAsync(ws + 65536, 0, 393216, stream);

    // 4. affinity in 16384-row quarters: dg -> fused gemm -> w_acc
    for (int qi = 0; qi < 4; ++qi) {
        pair_kernel<<<dim3(8192), 256, 0, stream>>>(
            f_g, f_g, s0, o0, dbuf, qi * 16384);
        gemm_blds<<<dim3(512), 512, 0, stream>>>(
            dbuf, sfcT, nullptr, 512, 8, 8, s3, o3, 1,
            scl_W, w_acc + qi * 16384);
    }
    // 5. wT[g2][g1] = bf16(w[g1][g2] + scl_b)
    wconv_kernel<<<dim3(256), 256, 0, stream>>>(w_acc, scl_b, wT);

    // 6. probe chunks
    for (int ci = 0; ci < nc; ++ci) {
        pair_kernel<<<dim3(R / 2), 256, 0, stream>>>(
            f_p, f_g, s0, o0, dbuf, ci * R);
        gemm_blds<<<dim3((R / 256) * 16), 512, 0, stream>>>(
            dbuf, W1T, hbuf, 1024, 16, R / 2048, s1, o1, 1, nullptr, nullptr);
        gemm_blds<<<dim3((R / 256) * 16), 512, 0, stream>>>(
            hbuf, W2T, tbuf, 1024, 16, R / 2048, s2, o2, 1, nullptr, nullptr);
        gemm_blds<<<dim3((R / 256) * 8), 512, 0, stream>>>(
            tbuf, ffcT, ubuf, 512, 8, R / 2048, nullptr, nullptr, 0, nullptr, nullptr);
        utrans_kernel<<<dim3(4, 8, pc), 256, 0, stream>>>(ubuf, dbuf);
        gemm_kernel<<<dim3(8, 2, pc), 256, 0, stream>>>(
            wT, dbuf, nullptr, 256, 512, (long long)512 * 256, 0,
            s4, o4, 1, cls_W, out_acc + (size_t)ci * pc * 256, 256);
    }
    // 7. d_out = out_acc + cls_b
    finout_kernel<<<dim3(128), 256, 0, stream>>>(out_acc, cls_b, (float*)d_out);
}

// Round 7
// 1206.353 us; speedup vs baseline: 1.0062x; 1.0062x over previous
//
#include <hip/hip_runtime.h>

// Sggnn_23218593202512 — round 7: manually software-pipelined barrier-free
// K-loop. R6's gemm_blds was depth-0 pipelined (VGPR=52): every iter stalls
// ~300cyc on A global loads before 38cyc of MFMA -> MfmaUtil 9.6%. Now:
// A-frags prefetched 2 iters ahead (afb[2][4]+tmpA, crossing the K-half
// boundary), B-frags 1 iter ahead from LDS (bfb[2][2]). Indexing identical
// to R6 (verified). Everything else unchanged from R6 except comments.

typedef __bf16 bf16;
typedef __attribute__((ext_vector_type(8))) __bf16 bf16x8;
typedef __attribute__((ext_vector_type(4))) float f32x4;

#define EPSV 1e-5f

__device__ __forceinline__ void async_load16(const bf16* g, bf16* l) {
    __builtin_amdgcn_global_load_lds(
        (const __attribute__((address_space(1))) void*)g,
        (__attribute__((address_space(3))) void*)l, 16, 0, 0);
}

__global__ __launch_bounds__(256) void prep_kernel(
    const float* __restrict__ g, const float* __restrict__ b,
    const float* __restrict__ m, const float* __restrict__ v,
    const float* __restrict__ bias, float* __restrict__ scale,
    float* __restrict__ offset, int n)
{
    int i = blockIdx.x * 256 + threadIdx.x;
    if (i >= n) return;
    float s = g[i] / sqrtf(v[i] + EPSV);
    float o = b[i] - m[i] * s;
    if (bias) o += bias[i] * s;
    scale[i] = s;
    offset[i] = o;
}

__global__ __launch_bounds__(256) void wtrans_kernel(
    const float* __restrict__ in, bf16* __restrict__ out, int K, int N)
{
    int k = blockIdx.x * 256 + threadIdx.x;
    int n = blockIdx.y;
    out[(size_t)n * K + k] = (bf16)in[(size_t)k * N + n];
}

// D[r][kc..kc+7] = bf16((X[(roff+r)>>8][k]-Y[(roff+r)&255][k])^2*ps[k]+po[k])
__global__ __launch_bounds__(256) void pair_kernel(
    const float* __restrict__ X, const float* __restrict__ Y,
    const float* __restrict__ ps, const float* __restrict__ po,
    bf16* __restrict__ D, int roff)
{
    int gid = blockIdx.x * 256 + threadIdx.x;
    int r = gid >> 7, kc = (gid & 127) * 8;
    int rg = roff + r;
    const float* xp = X + (size_t)(rg >> 8) * 1024 + kc;
    const float* yp = Y + (size_t)(rg & 255) * 1024 + kc;
    f32x4 x0 = *(const f32x4*)xp, x1 = *(const f32x4*)(xp + 4);
    f32x4 y0 = *(const f32x4*)yp, y1 = *(const f32x4*)(yp + 4);
    f32x4 sa = *(const f32x4*)(ps + kc), sb = *(const f32x4*)(ps + kc + 4);
    f32x4 oa = *(const f32x4*)(po + kc), ob = *(const f32x4*)(po + kc + 4);
    bf16x8 dv;
#pragma unroll
    for (int j = 0; j < 4; ++j) {
        float d0 = x0[j] - y0[j], d1 = x1[j] - y1[j];
        dv[j]     = (bf16)(d0 * d0 * sa[j] + oa[j]);
        dv[j + 4] = (bf16)(d1 * d1 * sb[j] + ob[j]);
    }
    *(bf16x8*)(D + (size_t)r * 1024 + kc) = dv;
}

// wT[g2*256+g1] = bf16(w_acc[g1*256+g2] + scl_b)
__global__ __launch_bounds__(256) void wconv_kernel(
    const float* __restrict__ w_acc, const float* __restrict__ sclb,
    bf16* __restrict__ wT)
{
    int tid = blockIdx.x * 256 + threadIdx.x;
    int g2 = tid >> 8, g1 = tid & 255;
    wT[tid] = (bf16)(w_acc[g1 * 256 + g2] + sclb[0]);
}

__global__ __launch_bounds__(256) void utrans_kernel(
    const bf16* __restrict__ u, bf16* __restrict__ uT)
{
    __shared__ float tile[64][65];
    int g0 = blockIdx.x * 64, h0 = blockIdx.y * 64, p = blockIdx.z;
    const bf16* up = u + (size_t)p * 256 * 512;
    bf16* op = uT + (size_t)p * 512 * 256;
    for (int c = threadIdx.x; c < 512; c += 256) {
        int r = c >> 3, hc = (c & 7) * 8;
        bf16x8 val = *(const bf16x8*)(up + (size_t)(g0 + r) * 512 + h0 + hc);
#pragma unroll
        for (int j = 0; j < 8; ++j) tile[r][hc + j] = (float)val[j];
    }
    __syncthreads();
    for (int c = threadIdx.x; c < 512; c += 256) {
        int hr = c >> 3, gc = (c & 7) * 8;
        bf16x8 val;
#pragma unroll
        for (int j = 0; j < 8; ++j) val[j] = (bf16)tile[gc + j][hr];
        *(bf16x8*)(op + (size_t)(h0 + hr) * 256 + g0 + gc) = val;
    }
}

__global__ __launch_bounds__(256) void finout_kernel(
    const float* __restrict__ acc, const float* __restrict__ clsb,
    float* __restrict__ out)
{
    int i = blockIdx.x * 256 + threadIdx.x;
    out[i] = acc[i] + clsb[0];
}

// ---------- pipelined barrier-free-K GEMM: C = epi(A[M,1024] @ BT[N,1024]^T)
// 512 thr = 8 waves (4 row x 2 col), wave tile 64x32 (acc[4][2]).
// B half-panel 64x512 LDS-resident (64 KiB, XOR-swizzled); A streamed via
// registers with DEPTH-2 prefetch (incl. across the K-half boundary);
// B-frags DEPTH-1 prefetch. No barriers inside the 16-iter K-loop.
__global__ __launch_bounds__(512) void gemm_blds(
    const bf16* __restrict__ A, const bf16* __restrict__ BT,
    bf16* __restrict__ C, int N, int nColB, int nRowBdiv8,
    const float* __restrict__ scale, const float* __restrict__ offset,
    int lrelu, const float* __restrict__ fuseW, float* __restrict__ facc)
{
    __shared__ bf16 Bs[64 * 512];   // 64 KiB
    const int tid  = threadIdx.x;
    const int lane = tid & 63;
    const int wave = tid >> 6;
    const int wrow = wave >> 1, wcol = wave & 1;
    const int q = lane >> 4, l16 = lane & 15;

    int b = blockIdx.x;
    int xcd = b & 7, j = b >> 3;
    int colb = j % nColB, rl = j / nColB;
    int rowb = xcd * nRowBdiv8 + rl;
    const int row0 = rowb * 256, col0 = colb * 64;

    f32x4 acc[4][2];
#pragma unroll
    for (int mi = 0; mi < 4; ++mi)
#pragma unroll
        for (int ni = 0; ni < 2; ++ni)
#pragma unroll
            for (int e = 0; e < 4; ++e) acc[mi][ni][e] = 0.f;

    const bf16* Arow[4];
#pragma unroll
    for (int mi = 0; mi < 4; ++mi)
        Arow[mi] = A + (size_t)(row0 + wrow * 64 + mi * 16 + l16) * 1024 + q * 8;

    bf16x8 afb[2][4], bfb[2][2];
    // initial A prefetch: kh=0 iters 0,1
#pragma unroll
    for (int mi = 0; mi < 4; ++mi) afb[0][mi] = *(const bf16x8*)(Arow[mi]);
#pragma unroll
    for (int mi = 0; mi < 4; ++mi) afb[1][mi] = *(const bf16x8*)(Arow[mi] + 32);

#pragma unroll
    for (int kh = 0; kh < 2; ++kh) {
        // stage B half-panel: 64 cols x 512 K, stored chunk = global ^ (c&7)
#pragma unroll
        for (int i = 0; i < 8; ++i) {
            int idx = i * 512 + tid;            // 4096 16B-chunks
            int c = idx >> 6, chs = idx & 63;
            int ch = chs ^ (c & 7);
            async_load16(BT + (size_t)(col0 + c) * 1024 + kh * 512 + ch * 8,
                         &Bs[idx * 8]);
        }
        __syncthreads();   // vmcnt(0) drain also completes A prefetches

        // B-frag prefetch for it=0
#pragma unroll
        for (int ni = 0; ni < 2; ++ni) {
            int c = wcol * 32 + ni * 16 + l16;
            int chs = q ^ (c & 7);
            bfb[0][ni] = *(const bf16x8*)&Bs[(c * 64 + chs) * 8];
        }

#pragma unroll
        for (int it = 0; it < 16; ++it) {
            const int cur = it & 1;
            // prefetch next B-frags (depth 1, from LDS)
            if (it + 1 < 16) {
#pragma unroll
                for (int ni = 0; ni < 2; ++ni) {
                    int c = wcol * 32 + ni * 16 + l16;
                    int chs = ((it + 1) * 4 + q) ^ (c & 7);
                    bfb[cur ^ 1][ni] = *(const bf16x8*)&Bs[(c * 64 + chs) * 8];
                }
            }
            // prefetch A-frags (depth 2, crossing the half boundary)
            bf16x8 tmpA[4];
            const bool pf = (it + 2 < 16) || (kh == 0);
            const int ko = (it + 2 < 16) ? (kh * 512 + (it + 2) * 32)
                                         : (512 + (it - 14) * 32);
            if (pf) {
#pragma unroll
                for (int mi = 0; mi < 4; ++mi)
                    tmpA[mi] = *(const bf16x8*)(Arow[mi] + ko);
            }
            // MFMAs
#pragma unroll
            for (int mi = 0; mi < 4; ++mi)
#pragma unroll
                for (int ni = 0; ni < 2; ++ni)
                    acc[mi][ni] = __builtin_amdgcn_mfma_f32_16x16x32_bf16(
                        afb[cur][mi], bfb[cur][ni], acc[mi][ni], 0, 0, 0);
            if (pf) {
#pragma unroll
                for (int mi = 0; mi < 4; ++mi) afb[cur][mi] = tmpA[mi];
            }
        }
        __syncthreads();
    }

    // C/D layout: col = lane&15, row = (lane>>4)*4 + reg
    if (fuseW) {
#pragma unroll
        for (int mi = 0; mi < 4; ++mi)
#pragma unroll
            for (int i = 0; i < 4; ++i) {
                float rs = 0.f;
#pragma unroll
                for (int ni = 0; ni < 2; ++ni) {
                    int cc = col0 + wcol * 32 + ni * 16 + l16;
                    float val = acc[mi][ni][i] * scale[cc] + offset[cc];
                    val = val > 0.f ? val : 0.1f * val;
                    rs += val * fuseW[cc];
                }
                rs += __shfl_xor(rs, 1, 64);
                rs += __shfl_xor(rs, 2, 64);
                rs += __shfl_xor(rs, 4, 64);
                rs += __shfl_xor(rs, 8, 64);
                if (l16 == 0) {
                    int r = row0 + wrow * 64 + mi * 16 + q * 4 + i;
                    atomicAdd(facc + r, rs);
                }
            }
        return;
    }
#pragma unroll
    for (int mi = 0; mi < 4; ++mi)
#pragma unroll
        for (int ni = 0; ni < 2; ++ni)
#pragma unroll
            for (int i = 0; i < 4; ++i) {
                int r = row0 + wrow * 64 + mi * 16 + q * 4 + i;
                int cc = col0 + wcol * 32 + ni * 16 + l16;
                float val = acc[mi][ni][i];
                if (scale) val = val * scale[cc] + offset[cc];
                if (lrelu) val = val > 0.f ? val : 0.1f * val;
                C[(size_t)r * N + cc] = (bf16)val;
            }
}

// ---------- R5-structure gemm (verified) for the batched featfused stage ---
__global__ __launch_bounds__(256) void gemm_kernel(
    const bf16* __restrict__ A,
    const bf16* __restrict__ BT, bf16* __restrict__ C,
    int K, int N, long long batchB, long long batchC,
    const float* __restrict__ scale, const float* __restrict__ offset,
    int lrelu, const float* __restrict__ fuseW, float* __restrict__ facc,
    long long faccStride)
{
    __shared__ bf16 As[128 * 64];
    __shared__ bf16 Bs[64 * 64];
    const int tid  = threadIdx.x;
    const int lane = tid & 63;
    const int wave = tid >> 6;
    const int wr = wave >> 1, wc = wave & 1;
    const int row0 = blockIdx.y * 128;
    const int col0 = blockIdx.x * 64;
    const int q = lane >> 4, l16 = lane & 15;
    const int arow = lane >> 3;
    const int gch  = (lane & 7) ^ (arow & 7);

    const bf16* Bp = BT + (size_t)blockIdx.z * (size_t)batchB;
    bf16* Cp = C + (size_t)blockIdx.z * (size_t)batchC;

    f32x4 acc[4][2];
#pragma unroll
    for (int mi = 0; mi < 4; ++mi)
#pragma unroll
        for (int ni = 0; ni < 2; ++ni)
#pragma unroll
            for (int e = 0; e < 4; ++e) acc[mi][ni][e] = 0.f;

    for (int kk = 0; kk < K; kk += 64) {
#pragma unroll
        for (int t = 0; t < 4; ++t) {
            int j = wave * 4 + t;
            async_load16(A + (size_t)(row0 + j * 8 + arow) * K + kk + gch * 8,
                         &As[j * 512 + lane * 8]);
        }
#pragma unroll
        for (int t = 0; t < 2; ++t) {
            int j = wave * 2 + t;
            async_load16(Bp + (size_t)(col0 + j * 8 + arow) * K + kk + gch * 8,
                         &Bs[j * 512 + lane * 8]);
        }
        __syncthreads();
#pragma unroll
        for (int s = 0; s < 2; ++s) {
            bf16x8 af[4], bfr[2];
#pragma unroll
            for (int mi = 0; mi < 4; ++mi) {
                int r = wr * 64 + mi * 16 + l16;
                af[mi] = *(const bf16x8*)&As[r * 64 + (((s * 4 + q) ^ (r & 7)) * 8)];
            }
#pragma unroll
            for (int ni = 0; ni < 2; ++ni) {
                int rc = wc * 32 + ni * 16 + l16;
                bfr[ni] = *(const bf16x8*)&Bs[rc * 64 + (((s * 4 + q) ^ (rc & 7)) * 8)];
            }
#pragma unroll
            for (int mi = 0; mi < 4; ++mi)
#pragma unroll
                for (int ni = 0; ni < 2; ++ni)
                    acc[mi][ni] = __builtin_amdgcn_mfma_f32_16x16x32_bf16(
                        af[mi], bfr[ni], acc[mi][ni], 0, 0, 0);
        }
        __syncthreads();
    }

    if (fuseW) {
#pragma unroll
        for (int mi = 0; mi < 4; ++mi)
#pragma unroll
            for (int i = 0; i < 4; ++i) {
                float rs = 0.f;
#pragma unroll
                for (int ni = 0; ni < 2; ++ni) {
                    int cc = col0 + wc * 32 + ni * 16 + l16;
                    float val = acc[mi][ni][i] * scale[cc] + offset[cc];
                    val = val > 0.f ? val : 0.1f * val;
                    rs += val * fuseW[cc];
                }
                rs += __shfl_xor(rs, 1, 64);
                rs += __shfl_xor(rs, 2, 64);
                rs += __shfl_xor(rs, 4, 64);
                rs += __shfl_xor(rs, 8, 64);
                if (l16 == 0) {
                    int r = row0 + wr * 64 + mi * 16 + q * 4 + i;
                    atomicAdd(facc + (size_t)blockIdx.z * faccStride + r, rs);
                }
            }
        return;
    }
#pragma unroll
    for (int mi = 0; mi < 4; ++mi)
#pragma unroll
        for (int ni = 0; ni < 2; ++ni)
#pragma unroll
            for (int i = 0; i < 4; ++i) {
                int r = row0 + wr * 64 + mi * 16 + q * 4 + i;
                int cc = col0 + wc * 32 + ni * 16 + l16;
                float val = acc[mi][ni][i];
                if (scale) val = val * scale[cc] + offset[cc];
                if (lrelu) val = val > 0.f ? val : 0.1f * val;
                Cp[(size_t)r * N + cc] = (bf16)val;
            }
}

extern "C" void kernel_launch(void* const* d_in, const int* in_sizes, int n_in,
                              void* d_out, int out_size, void* d_ws, size_t ws_size,
                              hipStream_t stream)
{
    const float* f_p   = (const float*)d_in[0];
    const float* f_g   = (const float*)d_in[1];
    const float* bn_g  = (const float*)d_in[2];
    const float* bn_b  = (const float*)d_in[3];
    const float* bn_m  = (const float*)d_in[4];
    const float* bn_v  = (const float*)d_in[5];
    const float* rf_W1 = (const float*)d_in[6];
    const float* rf_b1 = (const float*)d_in[7];
    const float* rf1_g = (const float*)d_in[8];
    const float* rf1_b = (const float*)d_in[9];
    const float* rf1_m = (const float*)d_in[10];
    const float* rf1_v = (const float*)d_in[11];
    const float* rf_W2 = (const float*)d_in[12];
    const float* rf_b2 = (const float*)d_in[13];
    const float* rf2_g = (const float*)d_in[14];
    const float* rf2_b = (const float*)d_in[15];
    const float* rf2_m = (const float*)d_in[16];
    const float* rf2_v = (const float*)d_in[17];
    const float* sfc_W = (const float*)d_in[18];
    const float* sfc_b = (const float*)d_in[19];
    const float* sbn_g = (const float*)d_in[20];
    const float* sbn_b = (const float*)d_in[21];
    const float* sbn_m = (const float*)d_in[22];
    const float* sbn_v = (const float*)d_in[23];
    const float* scl_W = (const float*)d_in[24];
    const float* scl_b = (const float*)d_in[25];
    const float* ffc_W = (const float*)d_in[26];
    const float* ffc_b = (const float*)d_in[27];
    const float* fbn_g = (const float*)d_in[28];
    const float* fbn_b = (const float*)d_in[29];
    const float* fbn_m = (const float*)d_in[30];
    const float* fbn_v = (const float*)d_in[31];
    const float* cls_W = (const float*)d_in[32];
    const float* cls_b = (const float*)d_in[33];

    const size_t MB = 1ull << 20;
    char* ws = (char*)d_ws;
    float* SC      = (float*)(ws);
    float *s0 = SC,        *o0 = SC + 1024;
    float *s1 = SC + 2048, *o1 = SC + 3072;
    float *s2 = SC + 4096, *o2 = SC + 5120;
    float *s3 = SC + 6144, *o3 = SC + 6656;
    float *s4 = SC + 7168, *o4 = SC + 7680;
    float* w_acc   = (float*)(ws + 65536);       // 256 KiB
    float* out_acc = (float*)(ws + 327680);      // 128 KiB
    bf16* wT       = (bf16*)(ws + 458752);       // 128 KiB
    bf16* W1T      = (bf16*)(ws + 1 * MB);
    bf16* W2T      = (bf16*)(ws + 3 * MB);
    bf16* sfcT     = (bf16*)(ws + 5 * MB);
    bf16* ffcT     = (bf16*)(ws + 6 * MB);

    int nc = (ws_size >= 125 * MB) ? 2 : 4;
    const int pc = 128 / nc;
    const int R  = pc * 256;                     // rows per probe chunk
    const size_t dsz = (size_t)R * 1024 * 2;
    bf16* dbuf = (bf16*)(ws + 8 * MB);           // d / dg-quarter / uT
    bf16* hbuf = (bf16*)(ws + 8 * MB + dsz);
    bf16* tbuf = (bf16*)(ws + 8 * MB + 2 * dsz);
    bf16* ubuf = (bf16*)(ws + 8 * MB + 3 * dsz);

    // 1. BN folds
    prep_kernel<<<dim3(4), 256, 0, stream>>>(bn_g, bn_b, bn_m, bn_v, nullptr, s0, o0, 1024);
    prep_kernel<<<dim3(4), 256, 0, stream>>>(rf1_g, rf1_b, rf1_m, rf1_v, rf_b1, s1, o1, 1024);
    prep_kernel<<<dim3(4), 256, 0, stream>>>(rf2_g, rf2_b, rf2_m, rf2_v, rf_b2, s2, o2, 1024);
    prep_kernel<<<dim3(2), 256, 0, stream>>>(sbn_g, sbn_b, sbn_m, sbn_v, sfc_b, s3, o3, 512);
    prep_kernel<<<dim3(2), 256, 0, stream>>>(fbn_g, fbn_b, fbn_m, fbn_v, ffc_b, s4, o4, 512);

    // 2. weight transposes
    wtrans_kernel<<<dim3(4, 1024), 256, 0, stream>>>(rf_W1, W1T, 1024, 1024);
    wtrans_kernel<<<dim3(4, 1024), 256, 0, stream>>>(rf_W2, W2T, 1024, 1024);
    wtrans_kernel<<<dim3(4, 512), 256, 0, stream>>>(sfc_W, sfcT, 1024, 512);
    wtrans_kernel<<<dim3(4, 512), 256, 0, stream>>>(ffc_W, ffcT, 1024, 512);

    // 3. zero accumulators
    hipMemsetAsync(ws + 65536, 0, 393216, stream);

    // 4. affinity in 16384-row quarters: dg -> fused gemm -> w_acc
    for (int qi = 0; qi < 4; ++qi) {
        pair_kernel<<<dim3(8192), 256, 0, stream>>>(
            f_g, f_g, s0, o0, dbuf, qi * 16384);
        gemm_blds<<<dim3(512), 512, 0, stream>>>(
            dbuf, sfcT, nullptr, 512, 8, 8, s3, o3, 1,
            scl_W, w_acc + qi * 16384);
    }
    // 5. wT[g2][g1] = bf16(w[g1][g2] + scl_b)
    wconv_kernel<<<dim3(256), 256, 0, stream>>>(w_acc, scl_b, wT);

    // 6. probe chunks
    for (int ci = 0; ci < nc; ++ci) {
        pair_kernel<<<dim3(R / 2), 256, 0, stream>>>(
            f_p, f_g, s0, o0, dbuf, ci * R);
        gemm_blds<<<dim3((R / 256) * 16), 512, 0, stream>>>(
            dbuf, W1T, hbuf, 1024, 16, R / 2048, s1, o1, 1, nullptr, nullptr);
        gemm_blds<<<dim3((R / 256) * 16), 512, 0, stream>>>(
            hbuf, W2T, tbuf, 1024, 16, R / 2048, s2, o2, 1, nullptr, nullptr);
        gemm_blds<<<dim3((R / 256) * 8), 512, 0, stream>>>(
            tbuf, ffcT, ubuf, 512, 8, R / 2048, nullptr, nullptr, 0, nullptr, nullptr);
        utrans_kernel<<<dim3(4, 8, pc), 256, 0, stream>>>(ubuf, dbuf);
        gemm_kernel<<<dim3(8, 2, pc), 256, 0, stream>>>(
            wT, dbuf, nullptr, 256, 512, (long long)512 * 256, 0,
            s4, o4, 1, cls_W, out_acc + (size_t)ci * pc * 256, 256);
    }
    // 7. d_out = out_acc + cls_b
    finout_kernel<<<dim3(128), 256, 0, stream>>>(out_acc, cls_b, (float*)d_out);
}

// Round 8
// 651.029 us; speedup vs baseline: 1.8645x; 1.8530x over previous
//
#include <hip/hip_runtime.h>

// Sggnn_23218593202512 — round 8: R4 (best, 656us) + BK=64. R5-R7 showed the
// limiter is load-stalls per K-iter: throughput tracks MFMA-work per stall.
// BK=64 halves barrier/vmcnt(0) drains (16 iters, 32 wave-MFMAs per iter).
// XOR chunk swizzle (verified R5/R6, conflicts~0) for stride-64 LDS rows,
// folded into the DMA global source address. All else identical to R4:
// 128x128 block tile, 4 waves 2x2 of 64x64, pair-mode fused staging,
// symmetric affinity skip, fused classifier epilogue, nc=1.

typedef __bf16 bf16;
typedef __attribute__((ext_vector_type(8))) __bf16 bf16x8;
typedef __attribute__((ext_vector_type(4))) float f32x4;

#define EPSV 1e-5f

__device__ __forceinline__ void async_load16(const bf16* g, bf16* l) {
    __builtin_amdgcn_global_load_lds(
        (const __attribute__((address_space(1))) void*)g,
        (__attribute__((address_space(3))) void*)l, 16, 0, 0);
}

__global__ __launch_bounds__(256) void prep_kernel(
    const float* __restrict__ g, const float* __restrict__ b,
    const float* __restrict__ m, const float* __restrict__ v,
    const float* __restrict__ bias, float* __restrict__ scale,
    float* __restrict__ offset, int n)
{
    int i = blockIdx.x * 256 + threadIdx.x;
    if (i >= n) return;
    float s = g[i] / sqrtf(v[i] + EPSV);
    float o = b[i] - m[i] * s;
    if (bias) o += bias[i] * s;
    scale[i] = s;
    offset[i] = o;
}

__global__ __launch_bounds__(256) void wtrans_kernel(
    const float* __restrict__ in, bf16* __restrict__ out, int K, int N)
{
    int k = blockIdx.x * 256 + threadIdx.x;
    int n = blockIdx.y;
    out[(size_t)n * K + k] = (bf16)in[(size_t)k * N + n];
}

// wT[g2*256+g1] = bf16(w[g1][g2] + scl_b); skipped quadrant mirrored
__global__ __launch_bounds__(256) void wconv_kernel(
    const float* __restrict__ w_acc, const float* __restrict__ sclb,
    bf16* __restrict__ wT)
{
    int tid = blockIdx.x * 256 + threadIdx.x;   // 0..65535
    int g2 = tid >> 8, g1 = tid & 255;
    int idx = (g1 >= 128 && g2 < 128) ? (g2 * 256 + g1) : (g1 * 256 + g2);
    wT[tid] = (bf16)(w_acc[idx] + sclb[0]);
}

__global__ __launch_bounds__(256) void utrans_kernel(
    const bf16* __restrict__ u, bf16* __restrict__ uT)
{
    __shared__ float tile[64][65];
    int g0 = blockIdx.x * 64, h0 = blockIdx.y * 64, p = blockIdx.z;
    const bf16* up = u + (size_t)p * 256 * 512;
    bf16* op = uT + (size_t)p * 512 * 256;
    for (int c = threadIdx.x; c < 512; c += 256) {
        int r = c >> 3, hc = (c & 7) * 8;
        bf16x8 val = *(const bf16x8*)(up + (size_t)(g0 + r) * 512 + h0 + hc);
#pragma unroll
        for (int j = 0; j < 8; ++j) tile[r][hc + j] = (float)val[j];
    }
    __syncthreads();
    for (int c = threadIdx.x; c < 512; c += 256) {
        int hr = c >> 3, gc = (c & 7) * 8;
        bf16x8 val;
#pragma unroll
        for (int j = 0; j < 8; ++j) val[j] = (bf16)tile[gc + j][hr];
        *(bf16x8*)(op + (size_t)(h0 + hr) * 256 + g0 + gc) = val;
    }
}

__global__ __launch_bounds__(256) void finout_kernel(
    const float* __restrict__ acc, const float* __restrict__ clsb,
    float* __restrict__ out)
{
    int i = blockIdx.x * 256 + threadIdx.x;
    out[i] = acc[i] + clsb[0];
}

// C[M,N] = epi(A[M,K] @ BT[N,K]^T). 128x128 block tile, BK=64, 4 waves 2x2,
// wave 64x64 via 4x4 mfma 16x16x32 (2 k-steps). LDS stride 64, XOR-swizzled
// 16B chunks (store chunk = global chunk ^ (row&7)).
// pair mode (pairX!=0, f32): A[r][k] = (X[r>>8][k]-Y[r&255][k])^2*ps[k]+po[k]
// symmap: blockIdx.y remap (symmetric affinity skip)
// fused (fuseW!=0): rs += lrelu(bn(val))*fuseW[col] -> atomicAdd facc
__global__ __launch_bounds__(256) void gemm_kernel(
    const bf16* __restrict__ A,
    const float* __restrict__ pairX, const float* __restrict__ pairY,
    const float* __restrict__ ps, const float* __restrict__ po,
    const bf16* __restrict__ BT,
    bf16* __restrict__ C,
    int K, int N,
    long long batchB, long long batchC,
    const float* __restrict__ scale, const float* __restrict__ offset,
    int lrelu, int symmap,
    const float* __restrict__ fuseW, float* __restrict__ facc,
    long long faccStride)
{
    __shared__ bf16 As[128 * 64];   // 16 KiB, swizzled
    __shared__ bf16 Bs[128 * 64];   // 16 KiB, swizzled
    const int tid  = threadIdx.x;
    const int lane = tid & 63;
    const int wave = tid >> 6;
    const int wr = wave >> 1, wc = wave & 1;
    int by = blockIdx.y;
    if (symmap) by = (by < 128) ? (by * 2) : ((by - 128) * 2 + 1);
    const int row0 = by * 128;
    const int col0 = blockIdx.x * 128;
    const int q = lane >> 4, l16 = lane & 15;
    // DMA lane mapping: task idx t (0..1023) = r*8+sch; per wave-issue 64
    // consecutive t; lane L covers r = base + (L>>3), stored chunk L&7,
    // global chunk = (L&7) ^ (r&7).
    const int drow = lane >> 3;                  // row offset within 8-row grp
    const int dsch = lane & 7;                   // stored chunk

    const bf16* Bp = BT + (size_t)blockIdx.z * (size_t)batchB;
    bf16* Cp = C + (size_t)blockIdx.z * (size_t)batchC;

    f32x4 acc[4][4];
#pragma unroll
    for (int mi = 0; mi < 4; ++mi)
#pragma unroll
        for (int ni = 0; ni < 4; ++ni)
#pragma unroll
            for (int e = 0; e < 4; ++e) acc[mi][ni][e] = 0.f;

    for (int kk = 0; kk < K; kk += 64) {
        if (pairX) {
#pragma unroll
            for (int t = 0; t < 4; ++t) {
                int c = tid + t * 256;      // 1024 tasks: r=c>>3, chunk=c&7
                int r = c >> 3, ch = c & 7;
                int gr = row0 + r;
                const float* xp = pairX + (size_t)(gr >> 8) * K + kk + ch * 8;
                const float* yp = pairY + (size_t)(gr & 255) * K + kk + ch * 8;
                f32x4 x0 = *(const f32x4*)xp, x1 = *(const f32x4*)(xp + 4);
                f32x4 y0 = *(const f32x4*)yp, y1 = *(const f32x4*)(yp + 4);
                f32x4 sa = *(const f32x4*)(ps + kk + ch * 8);
                f32x4 sb = *(const f32x4*)(ps + kk + ch * 8 + 4);
                f32x4 oa = *(const f32x4*)(po + kk + ch * 8);
                f32x4 ob = *(const f32x4*)(po + kk + ch * 8 + 4);
                bf16x8 dv;
#pragma unroll
                for (int j = 0; j < 4; ++j) {
                    float d0 = x0[j] - y0[j];
                    float d1 = x1[j] - y1[j];
                    dv[j]     = (bf16)(d0 * d0 * sa[j] + oa[j]);
                    dv[j + 4] = (bf16)(d1 * d1 * sb[j] + ob[j]);
                }
                *(bf16x8*)&As[r * 64 + ((ch ^ (r & 7)) * 8)] = dv;
            }
        } else {
#pragma unroll
            for (int t = 0; t < 4; ++t) {
                int grp = wave * 4 + t;     // 8-row group 0..15
                int r = grp * 8 + drow;
                int gch = dsch ^ (r & 7);
                async_load16(A + (size_t)(row0 + r) * K + kk + gch * 8,
                             &As[grp * 512 + lane * 8]);
            }
        }
#pragma unroll
        for (int t = 0; t < 4; ++t) {
            int grp = wave * 4 + t;
            int r = grp * 8 + drow;
            int gch = dsch ^ (r & 7);
            async_load16(Bp + (size_t)(col0 + r) * K + kk + gch * 8,
                         &Bs[grp * 512 + lane * 8]);
        }
        __syncthreads();

#pragma unroll
        for (int s = 0; s < 2; ++s) {       // two k-steps of 32
            bf16x8 af[4], bfr[4];
#pragma unroll
            for (int mi = 0; mi < 4; ++mi) {
                int r = wr * 64 + mi * 16 + l16;
                af[mi] = *(const bf16x8*)&As[r * 64 + (((s * 4 + q) ^ (r & 7)) * 8)];
            }
#pragma unroll
            for (int ni = 0; ni < 4; ++ni) {
                int rc = wc * 64 + ni * 16 + l16;
                bfr[ni] = *(const bf16x8*)&Bs[rc * 64 + (((s * 4 + q) ^ (rc & 7)) * 8)];
            }
#pragma unroll
            for (int mi = 0; mi < 4; ++mi)
#pragma unroll
                for (int ni = 0; ni < 4; ++ni)
                    acc[mi][ni] = __builtin_amdgcn_mfma_f32_16x16x32_bf16(
                        af[mi], bfr[ni], acc[mi][ni], 0, 0, 0);
        }
        __syncthreads();
    }

    // C/D layout (m89-verified): col = lane&15, row = (lane>>4)*4 + reg
    if (fuseW) {
#pragma unroll
        for (int mi = 0; mi < 4; ++mi)
#pragma unroll
            for (int i = 0; i < 4; ++i) {
                float rs = 0.f;
#pragma unroll
                for (int ni = 0; ni < 4; ++ni) {
                    int cc = col0 + wc * 64 + ni * 16 + l16;
                    float val = acc[mi][ni][i] * scale[cc] + offset[cc];
                    val = val > 0.f ? val : 0.1f * val;
                    rs += val * fuseW[cc];
                }
                rs += __shfl_xor(rs, 1, 64);
                rs += __shfl_xor(rs, 2, 64);
                rs += __shfl_xor(rs, 4, 64);
                rs += __shfl_xor(rs, 8, 64);
                if (l16 == 0) {
                    int r = row0 + wr * 64 + mi * 16 + q * 4 + i;
                    atomicAdd(facc + (size_t)blockIdx.z * faccStride + r, rs);
                }
            }
        return;
    }
#pragma unroll
    for (int mi = 0; mi < 4; ++mi)
#pragma unroll
        for (int ni = 0; ni < 4; ++ni)
#pragma unroll
            for (int i = 0; i < 4; ++i) {
                int r = row0 + wr * 64 + mi * 16 + q * 4 + i;
                int cc = col0 + wc * 64 + ni * 16 + l16;
                float val = acc[mi][ni][i];
                if (scale) val = val * scale[cc] + offset[cc];
                if (lrelu) val = val > 0.f ? val : 0.1f * val;
                Cp[(size_t)r * N + cc] = (bf16)val;
            }
}

extern "C" void kernel_launch(void* const* d_in, const int* in_sizes, int n_in,
                              void* d_out, int out_size, void* d_ws, size_t ws_size,
                              hipStream_t stream)
{
    const float* f_p   = (const float*)d_in[0];
    const float* f_g   = (const float*)d_in[1];
    const float* bn_g  = (const float*)d_in[2];
    const float* bn_b  = (const float*)d_in[3];
    const float* bn_m  = (const float*)d_in[4];
    const float* bn_v  = (const float*)d_in[5];
    const float* rf_W1 = (const float*)d_in[6];
    const float* rf_b1 = (const float*)d_in[7];
    const float* rf1_g = (const float*)d_in[8];
    const float* rf1_b = (const float*)d_in[9];
    const float* rf1_m = (const float*)d_in[10];
    const float* rf1_v = (const float*)d_in[11];
    const float* rf_W2 = (const float*)d_in[12];
    const float* rf_b2 = (const float*)d_in[13];
    const float* rf2_g = (const float*)d_in[14];
    const float* rf2_b = (const float*)d_in[15];
    const float* rf2_m = (const float*)d_in[16];
    const float* rf2_v = (const float*)d_in[17];
    const float* sfc_W = (const float*)d_in[18];
    const float* sfc_b = (const float*)d_in[19];
    const float* sbn_g = (const float*)d_in[20];
    const float* sbn_b = (const float*)d_in[21];
    const float* sbn_m = (const float*)d_in[22];
    const float* sbn_v = (const float*)d_in[23];
    const float* scl_W = (const float*)d_in[24];
    const float* scl_b = (const float*)d_in[25];
    const float* ffc_W = (const float*)d_in[26];
    const float* ffc_b = (const float*)d_in[27];
    const float* fbn_g = (const float*)d_in[28];
    const float* fbn_b = (const float*)d_in[29];
    const float* fbn_m = (const float*)d_in[30];
    const float* fbn_v = (const float*)d_in[31];
    const float* cls_W = (const float*)d_in[32];
    const float* cls_b = (const float*)d_in[33];

    const size_t MB = 1ull << 20;
    char* ws = (char*)d_ws;
    float* SC      = (float*)(ws);
    float *s0 = SC,        *o0 = SC + 1024;
    float *s1 = SC + 2048, *o1 = SC + 3072;
    float *s2 = SC + 4096, *o2 = SC + 5120;
    float *s3 = SC + 6144, *o3 = SC + 6656;
    float *s4 = SC + 7168, *o4 = SC + 7680;
    float* w_acc   = (float*)(ws + 65536);       // 256 KiB
    float* out_acc = (float*)(ws + 327680);      // 128 KiB
    bf16* wT       = (bf16*)(ws + 458752);       // 128 KiB
    bf16* W1T      = (bf16*)(ws + 1 * MB);
    bf16* W2T      = (bf16*)(ws + 3 * MB);
    bf16* sfcT     = (bf16*)(ws + 5 * MB);
    bf16* ffcT     = (bf16*)(ws + 6 * MB);

    int nc;
    if      (ws_size >= 170 * MB) nc = 1;
    else if (ws_size >= 90 * MB)  nc = 2;
    else if (ws_size >= 48 * MB)  nc = 4;
    else                          nc = 8;
    const int pc = 128 / nc;
    const int R  = pc * 256;
    const size_t hbytes = (size_t)R * 1024 * 2;
    bf16* bufA = (bf16*)(ws + 8 * MB);
    bf16* bufB = (bf16*)(ws + 8 * MB + hbytes);
    bf16* bufC = (bf16*)(ws + 8 * MB + 2 * hbytes);

    // 1. BN folds
    prep_kernel<<<dim3(4), 256, 0, stream>>>(bn_g, bn_b, bn_m, bn_v, nullptr, s0, o0, 1024);
    prep_kernel<<<dim3(4), 256, 0, stream>>>(rf1_g, rf1_b, rf1_m, rf1_v, rf_b1, s1, o1, 1024);
    prep_kernel<<<dim3(4), 256, 0, stream>>>(rf2_g, rf2_b, rf2_m, rf2_v, rf_b2, s2, o2, 1024);
    prep_kernel<<<dim3(2), 256, 0, stream>>>(sbn_g, sbn_b, sbn_m, sbn_v, sfc_b, s3, o3, 512);
    prep_kernel<<<dim3(2), 256, 0, stream>>>(fbn_g, fbn_b, fbn_m, fbn_v, ffc_b, s4, o4, 512);

    // 2. weight transposes (f32 -> bf16)
    wtrans_kernel<<<dim3(4, 1024), 256, 0, stream>>>(rf_W1, W1T, 1024, 1024);
    wtrans_kernel<<<dim3(4, 1024), 256, 0, stream>>>(rf_W2, W2T, 1024, 1024);
    wtrans_kernel<<<dim3(4, 512), 256, 0, stream>>>(sfc_W, sfcT, 1024, 512);
    wtrans_kernel<<<dim3(4, 512), 256, 0, stream>>>(ffc_W, ffcT, 1024, 512);

    // 3. zero accumulators (w_acc + out_acc contiguous)
    hipMemsetAsync(ws + 65536, 0, 393216, stream);

    // 4. fused+symmetric affinity: w[g1][g2] = sum_h lrelu(sbn(dg@sfc_W))*scl_W
    gemm_kernel<<<dim3(4, 384, 1), 256, 0, stream>>>(
        nullptr, f_g, f_g, s0, o0, sfcT, nullptr, 1024, 512, 0, 0,
        s3, o3, 1, 1, scl_W, w_acc, 0);
    // 5. wT[g2][g1] = bf16(w[canon] + scl_b)
    wconv_kernel<<<dim3(256), 256, 0, stream>>>(w_acc, scl_b, wT);

    // 6. probe chunks
    for (int ci = 0; ci < nc; ++ci) {
        const float* fp_c = f_p + (size_t)ci * pc * 1024;
        // h = lrelu(rf1(d @ W1 + b1))      [R,1024] -> bufA
        gemm_kernel<<<dim3(8, R / 128, 1), 256, 0, stream>>>(
            nullptr, fp_c, f_g, s0, o0, W1T, bufA, 1024, 1024, 0, 0,
            s1, o1, 1, 0, nullptr, nullptr, 0);
        // t = lrelu(rf2(h @ W2 + b2))      [R,1024] -> bufB
        gemm_kernel<<<dim3(8, R / 128, 1), 256, 0, stream>>>(
            bufA, nullptr, nullptr, nullptr, nullptr, W2T, bufB, 1024, 1024, 0, 0,
            s2, o2, 1, 0, nullptr, nullptr, 0);
        // u = t @ ffc_W                    [R,512] -> bufC
        gemm_kernel<<<dim3(4, R / 128, 1), 256, 0, stream>>>(
            bufB, nullptr, nullptr, nullptr, nullptr, ffcT, bufC, 1024, 512, 0, 0,
            nullptr, nullptr, 0, 0, nullptr, nullptr, 0);
        // uT[p][h][g]                      -> bufA
        utrans_kernel<<<dim3(4, 8, pc), 256, 0, stream>>>(bufC, bufA);
        // fused feat+classifier: lrelu(fbn(wT @ uT + b)) . cls_W -> out_acc
        gemm_kernel<<<dim3(4, 2, pc), 256, 0, stream>>>(
            wT, nullptr, nullptr, nullptr, nullptr, bufA, nullptr, 256, 512,
            (long long)512 * 256, 0, s4, o4, 1, 0,
            cls_W, out_acc + (size_t)ci * pc * 256, 256);
    }
    // 7. d_out = out_acc + cls_b
    finout_kernel<<<dim3(128), 256, 0, stream>>>(out_acc, cls_b, (float*)d_out);
}